// Round 1
// baseline (2688.798 us; speedup 1.0000x reference)
//
#include <hip/hip_runtime.h>
#include <cstdint>
#include <cmath>

#define PARTITIONABLE 1

constexpr int kPH = 12;
constexpr int kB = 16;
constexpr int kH = 256;
constexpr int kZ = 64;
constexpr int kCand = 512;
constexpr int kTopK = 64;
constexpr int kTools = 36;
constexpr int kRT = kB * kCand;   // 8192 rows
constexpr int kRows = 32;         // rows per rollout block
constexpr uint32_t kDiscTotal = (uint32_t)kCand * kPH * kB * kTools; // 3538944
constexpr uint32_t kContTotal = (uint32_t)kPH * kB * kCand * 2;      // 196608

// ---------------- Threefry-2x32 (JAX-exact: 20 rounds, 5 key injections) ---
__host__ __device__ inline void tf2x32(uint32_t k0, uint32_t k1,
                                       uint32_t x0, uint32_t x1,
                                       uint32_t& o0, uint32_t& o1) {
  uint32_t ks2 = k0 ^ k1 ^ 0x1BD11BDAu;
  x0 += k0; x1 += k1;
#define TFROT(v, d) (((v) << (d)) | ((v) >> (32 - (d))))
#define TFR(r) { x0 += x1; x1 = TFROT(x1, r); x1 ^= x0; }
  TFR(13) TFR(15) TFR(26) TFR(6)
  x0 += k1;  x1 += ks2 + 1u;
  TFR(17) TFR(29) TFR(16) TFR(24)
  x0 += ks2; x1 += k0 + 2u;
  TFR(13) TFR(15) TFR(26) TFR(6)
  x0 += k0;  x1 += k1 + 3u;
  TFR(17) TFR(29) TFR(16) TFR(24)
  x0 += k1;  x1 += ks2 + 4u;
  TFR(13) TFR(15) TFR(26) TFR(6)
  x0 += ks2; x1 += k0 + 5u;
#undef TFR
#undef TFROT
  o0 = x0; o1 = x1;
}

// random_bits(key, 32, shape) element at flat index idx (total = prod(shape))
__device__ inline uint32_t jax_bits32(uint32_t k0, uint32_t k1,
                                      uint32_t idx, uint32_t total) {
#if PARTITIONABLE
  (void)total;
  uint32_t y0, y1;
  tf2x32(k0, k1, 0u, idx, y0, y1);
  return y0 ^ y1;
#else
  uint32_t half = total >> 1;
  uint32_t y0, y1;
  if (idx < half) { tf2x32(k0, k1, idx, idx + half, y0, y1); return y0; }
  else            { tf2x32(k0, k1, idx - half, idx, y0, y1); return y1; }
#endif
}

// host: jax.random.split(key, 3)
static void host_split3(uint32_t k0, uint32_t k1, uint32_t out[3][2]) {
#if PARTITIONABLE
  for (uint32_t i = 0; i < 3; ++i)
    tf2x32(k0, k1, 0u, i, out[i][0], out[i][1]);
#else
  uint32_t a0,a1,b0,b1,c0,c1;
  tf2x32(k0, k1, 0u, 3u, a0, a1);
  tf2x32(k0, k1, 1u, 4u, b0, b1);
  tf2x32(k0, k1, 2u, 5u, c0, c1);
  out[0][0]=a0; out[0][1]=b0;
  out[1][0]=c0; out[1][1]=a1;
  out[2][0]=b1; out[2][1]=c1;
#endif
}

// ---------------- XLA f32 erf_inv (Giles polynomial) -----------------------
__device__ inline float erfinv_xla(float x) {
  float xx = x * x;
  float w = -(float)log1p((double)(-xx));
  float p;
  if (w < 5.0f) {
    float ww = w - 2.5f;
    p = 2.81022636e-08f;
    p = fmaf(p, ww, 3.43273939e-07f);
    p = fmaf(p, ww, -3.5233877e-06f);
    p = fmaf(p, ww, -4.39150654e-06f);
    p = fmaf(p, ww, 0.00021858087f);
    p = fmaf(p, ww, -0.00125372503f);
    p = fmaf(p, ww, -0.00417768164f);
    p = fmaf(p, ww, 0.246640727f);
    p = fmaf(p, ww, 1.50140941f);
  } else {
    float ww = sqrtf(w) - 3.0f;
    p = -0.000200214257f;
    p = fmaf(p, ww, 0.000100950558f);
    p = fmaf(p, ww, 0.00134934322f);
    p = fmaf(p, ww, -0.00367342844f);
    p = fmaf(p, ww, 0.00573950773f);
    p = fmaf(p, ww, -0.0076224613f);
    p = fmaf(p, ww, 0.00943887047f);
    p = fmaf(p, ww, 1.00167406f);
    p = fmaf(p, ww, 2.83297682f);
  }
  return p * x;
}

// ---------------- categorical sampling (disc actions) ----------------------
// gumbel shape (CAND, PH*B, NTOOLS); disc[ph][b*512+c] = argmax_t(g + logit)
__global__ __launch_bounds__(256) void k_sample_disc(
    uint32_t kd0, uint32_t kd1, const float* __restrict__ lfreq,
    float* __restrict__ discA, int it0) {
  int gid = blockIdx.x * 256 + threadIdx.x;   // gid = c*(PH*B) + j
  if (gid >= kCand * kPH * kB) return;
  int c = gid / (kPH * kB);
  int j = gid - c * (kPH * kB);               // j = ph*16 + b
  int best = 0;
  if (it0) {
    // logits are 0 (log of ones); gumbel is monotone in u -> exact int argmax
    uint32_t bm = 0u;
    for (int t = 0; t < kTools; ++t) {
      uint32_t bits = jax_bits32(kd0, kd1, (uint32_t)(gid * kTools + t), kDiscTotal);
      uint32_t m = bits >> 9;
      if (t == 0 || m > bm) { bm = m; best = t; }
    }
  } else {
    const float* lf = lfreq + j * kTools;
    float bv = 0.0f;
    for (int t = 0; t < kTools; ++t) {
      uint32_t bits = jax_bits32(kd0, kd1, (uint32_t)(gid * kTools + t), kDiscTotal);
      float u = __uint_as_float((bits >> 9) | 0x3F800000u) - 1.0f;
      if (u == 0.0f) u = 1.17549435e-38f;     // max(tiny, u) after *(1-tiny)+tiny
      float l1 = (float)log((double)u);       // < 0
      float g = -(float)log((double)(-l1));   // gumbel
      float val = g + lf[t];
      if (t == 0 || val > bv) { bv = val; best = t; }
    }
  }
  int ph = j >> 4, b = j & 15;
  discA[ph * kRT + b * kCand + c] = (float)best;
}

// ---------------- normal sampling (cont actions) ---------------------------
// noise shape (PH, B, CAND, CONT); cont = clip(mean + std*noise, -1, 1)
__global__ __launch_bounds__(256) void k_sample_cont(
    uint32_t kn0, uint32_t kn1, const float* __restrict__ meanv,
    const float* __restrict__ stdv, float* __restrict__ contA, int it0) {
  int gid = blockIdx.x * 256 + threadIdx.x;
  if (gid >= (int)kContTotal) return;
  uint32_t bits = jax_bits32(kn0, kn1, (uint32_t)gid, kContTotal);
  float f = __uint_as_float((bits >> 9) | 0x3F800000u) - 1.0f;
  const float lo = -0.99999994f;              // nextafter(-1, 0) in f32
  float u = fmaxf(lo, f * 2.0f + lo);         // (hi-lo) rounds to exactly 2.0f
  float n = __uint_as_float(0x3FB504F3u) * erfinv_xla(u);  // sqrt(2) f32
  int d = gid & 1;
  int c = (gid >> 1) & (kCand - 1);
  int rest = gid >> 10;                        // ph*16 + b
  int ph = rest >> 4, b = rest & 15;
  float m, s;
  if (it0) { m = 0.0f; s = 1.0f; }
  else {
    m = meanv[rest * 2 + d];
    s = stdv[rest * 2 + d];
  }
  float x = m + s * n;
  x = fminf(fmaxf(x, -1.0f), 1.0f);
  contA[(ph * kRT + b * kCand + c) * 2 + d] = x;
}

// ---------------- fused 12-step rollout ------------------------------------
// rows are independent: each block owns 32 rows for all 12 steps; belief tile
// lives in LDS; Wb (256KB) and Ws (64KB) stream from L2.
__global__ __launch_bounds__(256) void k_rollout(
    const float* __restrict__ belief,
    const float* __restrict__ discA, const float* __restrict__ contA,
    const float* __restrict__ Wb, const float* __restrict__ Wa,
    const float* __restrict__ bbv_, const float* __restrict__ Ws,
    const float* __restrict__ bs_, const float* __restrict__ wrb,
    const float* __restrict__ wrs, float* __restrict__ ret) {
  __shared__ float sB[kRows][kH];    // 32 KB
  __shared__ float sS[kRows][kZ];    // 8 KB
  __shared__ float aD[kRows], aC0[kRows], aC1[kRows];
  __shared__ float rets[kRows];
  const int tid = threadIdx.x;
  const int row0 = blockIdx.x * kRows;

  for (int i = tid; i < kRows * kH; i += 256) {
    int r = i >> 8, k = i & (kH - 1);
    sB[r][k] = belief[((row0 + r) >> 9) * kH + k];   // row -> batch = row/512
  }
  if (tid < kRows) rets[tid] = 0.0f;
  const int j = tid;                                 // owned belief column
  const float wa0 = Wa[j], wa1 = Wa[kH + j], wa2 = Wa[2 * kH + j];
  const float bbj = bbv_[j];
  const int j2 = tid & (kZ - 1);
  const int rg = tid >> 6;
  const float bsj = bs_[j2];
  __syncthreads();

  #pragma unroll 1
  for (int ph = 0; ph < kPH; ++ph) {
    if (tid < kRows) {
      int gr = row0 + tid;
      aD[tid]  = discA[ph * kRT + gr];
      aC0[tid] = contA[(ph * kRT + gr) * 2 + 0];
      aC1[tid] = contA[(ph * kRT + gr) * 2 + 1];
    }
    __syncthreads();
    // b' = tanh(b @ Wb + a @ Wa + bb), thread owns column j for 32 rows
    float acc[kRows];
    #pragma unroll
    for (int r = 0; r < kRows; ++r)
      acc[r] = bbj + aD[r] * wa0 + aC0[r] * wa1 + aC1[r] * wa2;
    for (int k0 = 0; k0 < kH; k0 += 4) {
      float w0 = Wb[(k0 + 0) * kH + j];
      float w1 = Wb[(k0 + 1) * kH + j];
      float w2 = Wb[(k0 + 2) * kH + j];
      float w3 = Wb[(k0 + 3) * kH + j];
      #pragma unroll
      for (int r = 0; r < kRows; ++r) {
        float4 b4 = *reinterpret_cast<const float4*>(&sB[r][k0]);
        acc[r] = fmaf(b4.x, w0, acc[r]);
        acc[r] = fmaf(b4.y, w1, acc[r]);
        acc[r] = fmaf(b4.z, w2, acc[r]);
        acc[r] = fmaf(b4.w, w3, acc[r]);
      }
    }
    #pragma unroll
    for (int r = 0; r < kRows; ++r) acc[r] = tanhf(acc[r]);
    __syncthreads();                     // everyone done reading old sB
    #pragma unroll
    for (int r = 0; r < kRows; ++r) sB[r][j] = acc[r];
    __syncthreads();
    // s = tanh(b' @ Ws + bs): thread -> (rows rg*8..+7, col j2)
    float sa[8];
    #pragma unroll
    for (int i = 0; i < 8; ++i) sa[i] = bsj;
    for (int jj = 0; jj < kH; jj += 4) {
      float v0 = Ws[(jj + 0) * kZ + j2];
      float v1 = Ws[(jj + 1) * kZ + j2];
      float v2 = Ws[(jj + 2) * kZ + j2];
      float v3 = Ws[(jj + 3) * kZ + j2];
      #pragma unroll
      for (int i = 0; i < 8; ++i) {
        float4 b4 = *reinterpret_cast<const float4*>(&sB[rg * 8 + i][jj]);
        sa[i] = fmaf(b4.x, v0, sa[i]);
        sa[i] = fmaf(b4.y, v1, sa[i]);
        sa[i] = fmaf(b4.z, v2, sa[i]);
        sa[i] = fmaf(b4.w, v3, sa[i]);
      }
    }
    #pragma unroll
    for (int i = 0; i < 8; ++i) sS[rg * 8 + i][j2] = tanhf(sa[i]);
    __syncthreads();
    // ret += b'@wrb + s@wrs (8 threads per row, shuffle-reduce)
    {
      int r = tid >> 3, l8 = tid & 7;
      float part = 0.0f;
      int kb = l8 * 32;
      #pragma unroll
      for (int k = 0; k < 32; ++k) part = fmaf(sB[r][kb + k], wrb[kb + k], part);
      int qb = l8 * 8;
      #pragma unroll
      for (int q = 0; q < 8; ++q) part = fmaf(sS[r][qb + q], wrs[qb + q], part);
      part += __shfl_xor(part, 1, 64);
      part += __shfl_xor(part, 2, 64);
      part += __shfl_xor(part, 4, 64);
      if (l8 == 0) rets[r] += part;
    }
    __syncthreads();
  }
  if (tid < kRows) ret[row0 + tid] = rets[tid];
}

// ---------------- per-batch top-k + statistics -----------------------------
__global__ __launch_bounds__(256) void k_topk_stats(
    const float* __restrict__ ret, const float* __restrict__ discA,
    const float* __restrict__ contA, float* __restrict__ freq,
    float* __restrict__ lfreq, float* __restrict__ meanv,
    float* __restrict__ stdv) {
  __shared__ float rv[kCand];
  __shared__ int selc[kTopK];
  __shared__ int hist[kTools];
  const int b = blockIdx.x, tid = threadIdx.x;
  for (int i = tid; i < kCand; i += 256) rv[i] = ret[b * kCand + i];
  __syncthreads();
  // exact lax.top_k set: rank by (value desc, index asc); deterministic selc
  for (int c = tid; c < kCand; c += 256) {
    float v = rv[c];
    int rank = 0;
    for (int o = 0; o < kCand; ++o) {
      float vo = rv[o];
      rank += ((vo > v) || (vo == v && o < c)) ? 1 : 0;
    }
    if (rank < kTopK) selc[rank] = c;
  }
  __syncthreads();
  for (int ph = 0; ph < kPH; ++ph) {
    if (tid < kTools) hist[tid] = 0;
    __syncthreads();
    if (tid < kTopK) {                    // exactly wave 0
      int c = selc[tid];
      int idx = ph * kRT + b * kCand + c;
      int d = (int)discA[idx];
      atomicAdd(&hist[d], 1);
      float c0 = contA[idx * 2 + 0];
      float c1 = contA[idx * 2 + 1];
      float s0 = c0, s1 = c1;
      #pragma unroll
      for (int sh = 1; sh < 64; sh <<= 1) {
        s0 += __shfl_xor(s0, sh, 64);
        s1 += __shfl_xor(s1, sh, 64);
      }
      float m0 = s0 * (1.0f / 64.0f);
      float m1 = s1 * (1.0f / 64.0f);
      float d0 = c0 - m0, d1 = c1 - m1;
      float q0 = d0 * d0, q1 = d1 * d1;
      #pragma unroll
      for (int sh = 1; sh < 64; sh <<= 1) {
        q0 += __shfl_xor(q0, sh, 64);
        q1 += __shfl_xor(q1, sh, 64);
      }
      if (tid == 0) {
        int o = (ph * kB + b) * 2;
        meanv[o + 0] = m0;
        meanv[o + 1] = m1;
        stdv[o + 0] = sqrtf(q0 * (1.0f / 64.0f));
        stdv[o + 1] = sqrtf(q1 * (1.0f / 64.0f));
      }
    }
    __syncthreads();
    if (tid < kTools) {
      float fq = (float)(hist[tid] + 1) / 100.0f;  // sum is always 64+36=100
      int o = (ph * kB + b) * kTools + tid;
      freq[o] = fq;
      lfreq[o] = (float)log((double)fq);
    }
    __syncthreads();
  }
}

// ---------------- final output ---------------------------------------------
__global__ void k_final(const float* __restrict__ freq,
                        const float* __restrict__ meanv,
                        float* __restrict__ out) {
  int b = threadIdx.x;
  if (b < kB) {
    const float* f = freq + b * kTools;   // ph = 0
    int best = 0; float bv = f[0];
    for (int t = 1; t < kTools; ++t)
      if (f[t] > bv) { bv = f[t]; best = t; }
    out[b * 3 + 0] = (float)best;
    out[b * 3 + 1] = meanv[b * 2 + 0];
    out[b * 3 + 2] = meanv[b * 2 + 1];
  }
}

extern "C" void kernel_launch(void* const* d_in, const int* in_sizes, int n_in,
                              void* d_out, int out_size, void* d_ws, size_t ws_size,
                              hipStream_t stream) {
  (void)in_sizes; (void)n_in; (void)out_size; (void)ws_size;
  const float* belief = (const float*)d_in[0];
  // d_in[1] (state) is mathematically unused: the carried s is never read.
  const float* Wb  = (const float*)d_in[2];
  const float* Wa  = (const float*)d_in[3];
  const float* bb  = (const float*)d_in[4];
  const float* Ws  = (const float*)d_in[5];
  const float* bs  = (const float*)d_in[6];
  const float* wrb = (const float*)d_in[7];
  const float* wrs = (const float*)d_in[8];
  float* out = (float*)d_out;

  float* w = (float*)d_ws;
  float* discA = w;                          // PH*RT           = 98304
  float* contA = discA + kPH * kRT;          // PH*RT*2         = 196608
  float* ret   = contA + kPH * kRT * 2;      // RT              = 8192
  float* freq  = ret + kRT;                  // PH*B*NTOOLS     = 6912
  float* lfreq = freq + kPH * kB * kTools;   // PH*B*NTOOLS     = 6912
  float* meanv = lfreq + kPH * kB * kTools;  // PH*B*2          = 384
  float* stdv  = meanv + kPH * kB * 2;       // PH*B*2          = 384

  uint32_t key0 = 0u, key1 = 42u;            // jax.random.key(42)
  for (int it = 0; it < 3; ++it) {
    uint32_t ks[3][2];
    host_split3(key0, key1, ks);             // k_disc, k_noise, key
    int it0 = (it == 0) ? 1 : 0;
    k_sample_disc<<<dim3((kCand * kPH * kB + 255) / 256), dim3(256), 0, stream>>>(
        ks[0][0], ks[0][1], lfreq, discA, it0);
    k_sample_cont<<<dim3((kContTotal + 255) / 256), dim3(256), 0, stream>>>(
        ks[1][0], ks[1][1], meanv, stdv, contA, it0);
    k_rollout<<<dim3(kRT / kRows), dim3(256), 0, stream>>>(
        belief, discA, contA, Wb, Wa, bb, Ws, bs, wrb, wrs, ret);
    k_topk_stats<<<dim3(kB), dim3(256), 0, stream>>>(
        ret, discA, contA, freq, lfreq, meanv, stdv);
    key0 = ks[2][0]; key1 = ks[2][1];
  }
  k_final<<<dim3(1), dim3(64), 0, stream>>>(freq, meanv, out);
}

// Round 2
// 1198.414 us; speedup vs baseline: 2.2436x; 2.2436x over previous
//
#include <hip/hip_runtime.h>
#include <cstdint>
#include <cmath>

#define PARTITIONABLE 1

constexpr int kPH = 12;
constexpr int kB = 16;
constexpr int kH = 256;
constexpr int kZ = 64;
constexpr int kCand = 512;
constexpr int kTopK = 64;
constexpr int kTools = 36;
constexpr int kRT = kB * kCand;   // 8192 rows
constexpr uint32_t kDiscTotal = (uint32_t)kCand * kPH * kB * kTools; // 3538944
constexpr uint32_t kContTotal = (uint32_t)kPH * kB * kCand * 2;      // 196608

constexpr int kRowsB = 16;        // rows per rollout block
constexpr int kStrideB = 20;      // padded LDS stride (words) for col-major belief

// ---------------- Threefry-2x32 (JAX-exact: 20 rounds, 5 key injections) ---
__host__ __device__ inline void tf2x32(uint32_t k0, uint32_t k1,
                                       uint32_t x0, uint32_t x1,
                                       uint32_t& o0, uint32_t& o1) {
  uint32_t ks2 = k0 ^ k1 ^ 0x1BD11BDAu;
  x0 += k0; x1 += k1;
#define TFROT(v, d) (((v) << (d)) | ((v) >> (32 - (d))))
#define TFR(r) { x0 += x1; x1 = TFROT(x1, r); x1 ^= x0; }
  TFR(13) TFR(15) TFR(26) TFR(6)
  x0 += k1;  x1 += ks2 + 1u;
  TFR(17) TFR(29) TFR(16) TFR(24)
  x0 += ks2; x1 += k0 + 2u;
  TFR(13) TFR(15) TFR(26) TFR(6)
  x0 += k0;  x1 += k1 + 3u;
  TFR(17) TFR(29) TFR(16) TFR(24)
  x0 += k1;  x1 += ks2 + 4u;
  TFR(13) TFR(15) TFR(26) TFR(6)
  x0 += ks2; x1 += k0 + 5u;
#undef TFR
#undef TFROT
  o0 = x0; o1 = x1;
}

__device__ inline uint32_t jax_bits32(uint32_t k0, uint32_t k1,
                                      uint32_t idx, uint32_t total) {
#if PARTITIONABLE
  (void)total;
  uint32_t y0, y1;
  tf2x32(k0, k1, 0u, idx, y0, y1);
  return y0 ^ y1;
#else
  uint32_t half = total >> 1;
  uint32_t y0, y1;
  if (idx < half) { tf2x32(k0, k1, idx, idx + half, y0, y1); return y0; }
  else            { tf2x32(k0, k1, idx - half, idx, y0, y1); return y1; }
#endif
}

static void host_split3(uint32_t k0, uint32_t k1, uint32_t out[3][2]) {
#if PARTITIONABLE
  for (uint32_t i = 0; i < 3; ++i)
    tf2x32(k0, k1, 0u, i, out[i][0], out[i][1]);
#else
  uint32_t a0,a1,b0,b1,c0,c1;
  tf2x32(k0, k1, 0u, 3u, a0, a1);
  tf2x32(k0, k1, 1u, 4u, b0, b1);
  tf2x32(k0, k1, 2u, 5u, c0, c1);
  out[0][0]=a0; out[0][1]=b0;
  out[1][0]=c0; out[1][1]=a1;
  out[2][0]=b1; out[2][1]=c1;
#endif
}

// ---------------- XLA f32 erf_inv (Giles polynomial) -----------------------
__device__ inline float erfinv_xla(float x) {
  float xx = x * x;
  float w = -(float)log1p((double)(-xx));
  float p;
  if (w < 5.0f) {
    float ww = w - 2.5f;
    p = 2.81022636e-08f;
    p = fmaf(p, ww, 3.43273939e-07f);
    p = fmaf(p, ww, -3.5233877e-06f);
    p = fmaf(p, ww, -4.39150654e-06f);
    p = fmaf(p, ww, 0.00021858087f);
    p = fmaf(p, ww, -0.00125372503f);
    p = fmaf(p, ww, -0.00417768164f);
    p = fmaf(p, ww, 0.246640727f);
    p = fmaf(p, ww, 1.50140941f);
  } else {
    float ww = sqrtf(w) - 3.0f;
    p = -0.000200214257f;
    p = fmaf(p, ww, 0.000100950558f);
    p = fmaf(p, ww, 0.00134934322f);
    p = fmaf(p, ww, -0.00367342844f);
    p = fmaf(p, ww, 0.00573950773f);
    p = fmaf(p, ww, -0.0076224613f);
    p = fmaf(p, ww, 0.00943887047f);
    p = fmaf(p, ww, 1.00167406f);
    p = fmaf(p, ww, 2.83297682f);
  }
  return p * x;
}

// ---------------- categorical sampling (disc actions) ----------------------
__global__ __launch_bounds__(256) void k_sample_disc(
    uint32_t kd0, uint32_t kd1, const float* __restrict__ lfreq,
    float* __restrict__ discA, int it0) {
  int gid = blockIdx.x * 256 + threadIdx.x;   // gid = c*(PH*B) + j
  if (gid >= kCand * kPH * kB) return;
  int c = gid / (kPH * kB);
  int j = gid - c * (kPH * kB);               // j = ph*16 + b
  int best = 0;
  if (it0) {
    uint32_t bm = 0u;
    for (int t = 0; t < kTools; ++t) {
      uint32_t bits = jax_bits32(kd0, kd1, (uint32_t)(gid * kTools + t), kDiscTotal);
      uint32_t m = bits >> 9;
      if (t == 0 || m > bm) { bm = m; best = t; }
    }
  } else {
    const float* lf = lfreq + j * kTools;
    float bv = 0.0f;
    for (int t = 0; t < kTools; ++t) {
      uint32_t bits = jax_bits32(kd0, kd1, (uint32_t)(gid * kTools + t), kDiscTotal);
      float u = __uint_as_float((bits >> 9) | 0x3F800000u) - 1.0f;
      if (u == 0.0f) u = 1.17549435e-38f;
      float l1 = (float)log((double)u);
      float g = -(float)log((double)(-l1));
      float val = g + lf[t];
      if (t == 0 || val > bv) { bv = val; best = t; }
    }
  }
  int ph = j >> 4, b = j & 15;
  discA[ph * kRT + b * kCand + c] = (float)best;
}

// ---------------- normal sampling (cont actions) ---------------------------
__global__ __launch_bounds__(256) void k_sample_cont(
    uint32_t kn0, uint32_t kn1, const float* __restrict__ meanv,
    const float* __restrict__ stdv, float* __restrict__ contA, int it0) {
  int gid = blockIdx.x * 256 + threadIdx.x;
  if (gid >= (int)kContTotal) return;
  uint32_t bits = jax_bits32(kn0, kn1, (uint32_t)gid, kContTotal);
  float f = __uint_as_float((bits >> 9) | 0x3F800000u) - 1.0f;
  const float lo = -0.99999994f;
  float u = fmaxf(lo, f * 2.0f + lo);
  float n = __uint_as_float(0x3FB504F3u) * erfinv_xla(u);
  int d = gid & 1;
  int c = (gid >> 1) & (kCand - 1);
  int rest = gid >> 10;                        // ph*16 + b
  int ph = rest >> 4, b = rest & 15;
  float m, s;
  if (it0) { m = 0.0f; s = 1.0f; }
  else {
    m = meanv[rest * 2 + d];
    s = stdv[rest * 2 + d];
  }
  float x = m + s * n;
  x = fminf(fmaxf(x, -1.0f), 1.0f);
  contA[(ph * kRT + b * kCand + c) * 2 + d] = x;
}

// ---------------- fused 12-step rollout (register-tiled outer-product) -----
// 512 blocks x 16 rows x 512 threads (8 waves): wave (kw,wc) handles k-half
// kw and column-quarter wc. Thread tile: 8 rows x 2 cols (16 fp32 acc).
// Belief is col-major in LDS ([k][r], stride 20 words); Wb/Ws stream from L2.
__global__ __launch_bounds__(512, 4) void k_rollout(
    const float* __restrict__ belief,
    const float* __restrict__ discA, const float* __restrict__ contA,
    const float* __restrict__ Wb, const float* __restrict__ Wa,
    const float* __restrict__ bbv_, const float* __restrict__ Ws,
    const float* __restrict__ bs_, const float* __restrict__ wrb,
    const float* __restrict__ wrs, float* __restrict__ ret) {
  __shared__ float sBc[kH * kStrideB];   // 20 KB col-major belief
  __shared__ float pT[kRowsB * kH];      // 16 KB partial / staging
  __shared__ float sAD[kRowsB], sA0[kRowsB], sA1[kRowsB];
  __shared__ float sret[kRowsB];

  const int tid = threadIdx.x;
  const int row0 = blockIdx.x * kRowsB;
  const int batch = row0 >> 9;

  const int w = tid >> 6;
  const int kw = w >> 2;            // k-half
  const int wc = w & 3;             // column quarter
  const int lane = tid & 63;
  const int lr = lane >> 5;         // 8-row group (0/1)
  const int lc = lane & 31;         // 2-col group
  const int r0 = lr * 8;
  const int c0 = wc * 64 + lc * 2;
  const int kbase = kw * 128;

  // Ws-stage lane mapping: 4 rows x 1 col
  const int lr2 = lane >> 4;        // 0..3
  const int lc2 = lane & 15;
  const int r0s = lr2 * 4;
  const int cs = wc * 16 + lc2;

  // per-thread loop-invariant parameters
  const float wa00 = Wa[c0],          wa01 = Wa[c0 + 1];
  const float wa10 = Wa[kH + c0],     wa11 = Wa[kH + c0 + 1];
  const float wa20 = Wa[2 * kH + c0], wa21 = Wa[2 * kH + c0 + 1];
  const float bb0 = bbv_[c0], bb1 = bbv_[c0 + 1];
  const float wrb0 = wrb[c0], wrb1 = wrb[c0 + 1];
  const float bsv = bs_[cs], wrsv = wrs[cs];

  for (int i = tid; i < kH * kRowsB; i += 512) {
    int k = i >> 4, r = i & (kRowsB - 1);
    sBc[k * kStrideB + r] = belief[batch * kH + k];
  }
  if (tid < kRowsB) sret[tid] = 0.0f;
  __syncthreads();

  #pragma unroll 1
  for (int ph = 0; ph < kPH; ++ph) {
    if (tid < kRowsB) {
      int gr = row0 + tid;
      sAD[tid] = discA[ph * kRT + gr];
      sA0[tid] = contA[(ph * kRT + gr) * 2 + 0];
      sA1[tid] = contA[(ph * kRT + gr) * 2 + 1];
    }
    __syncthreads();

    // ---- b' = tanh(b @ Wb + a @ Wa + bb): outer-product over k-half ----
    float acc[8][2];
    #pragma unroll
    for (int r = 0; r < 8; ++r) { acc[r][0] = 0.0f; acc[r][1] = 0.0f; }
    #pragma unroll 2
    for (int k = kbase; k < kbase + 128; ++k) {
      float4 a0 = *reinterpret_cast<const float4*>(&sBc[k * kStrideB + r0]);
      float4 a1 = *reinterpret_cast<const float4*>(&sBc[k * kStrideB + r0 + 4]);
      float2 w2 = *reinterpret_cast<const float2*>(&Wb[k * kH + c0]);
      float av[8] = {a0.x, a0.y, a0.z, a0.w, a1.x, a1.y, a1.z, a1.w};
      #pragma unroll
      for (int r = 0; r < 8; ++r) {
        acc[r][0] = fmaf(av[r], w2.x, acc[r][0]);
        acc[r][1] = fmaf(av[r], w2.y, acc[r][1]);
      }
    }
    if (kw == 1) {
      #pragma unroll
      for (int r = 0; r < 8; ++r) {
        pT[(r0 + r) * kH + c0]     = acc[r][0];
        pT[(r0 + r) * kH + c0 + 1] = acc[r][1];
      }
    }
    __syncthreads();   // pT ready; all reads of old sBc done

    if (kw == 0) {
      #pragma unroll
      for (int r = 0; r < 8; ++r) {
        int rb = r0 + r;
        float aD = sAD[rb], aC0 = sA0[rb], aC1 = sA1[rb];
        float t0 = acc[r][0] + pT[rb * kH + c0];
        float t1 = acc[r][1] + pT[rb * kH + c0 + 1];
        t0 += bb0 + aD * wa00 + aC0 * wa10 + aC1 * wa20;
        t1 += bb1 + aD * wa01 + aC0 * wa11 + aC1 * wa21;
        acc[r][0] = tanhf(t0);
        acc[r][1] = tanhf(t1);
      }
      // write b' back col-major
      float4 v;
      v = make_float4(acc[0][0], acc[1][0], acc[2][0], acc[3][0]);
      *reinterpret_cast<float4*>(&sBc[c0 * kStrideB + r0]) = v;
      v = make_float4(acc[4][0], acc[5][0], acc[6][0], acc[7][0]);
      *reinterpret_cast<float4*>(&sBc[c0 * kStrideB + r0 + 4]) = v;
      v = make_float4(acc[0][1], acc[1][1], acc[2][1], acc[3][1]);
      *reinterpret_cast<float4*>(&sBc[(c0 + 1) * kStrideB + r0]) = v;
      v = make_float4(acc[4][1], acc[5][1], acc[6][1], acc[7][1]);
      *reinterpret_cast<float4*>(&sBc[(c0 + 1) * kStrideB + r0 + 4]) = v;
    }
    __syncthreads();   // new belief visible

    // ---- s = tanh(b' @ Ws + bs): outer-product over k-half ----
    float sacc[4] = {0.0f, 0.0f, 0.0f, 0.0f};
    #pragma unroll 4
    for (int k = kbase; k < kbase + 128; ++k) {
      float4 a4 = *reinterpret_cast<const float4*>(&sBc[k * kStrideB + r0s]);
      float wv = Ws[k * kZ + cs];
      sacc[0] = fmaf(a4.x, wv, sacc[0]);
      sacc[1] = fmaf(a4.y, wv, sacc[1]);
      sacc[2] = fmaf(a4.z, wv, sacc[2]);
      sacc[3] = fmaf(a4.w, wv, sacc[3]);
    }
    if (kw == 1) {
      #pragma unroll
      for (int i = 0; i < 4; ++i) pT[(r0s + i) * kZ + cs] = sacc[i];
    }
    __syncthreads();   // s-partials ready

    if (kw == 0) {
      // returns: b' part (thread still holds b' in acc)
      float rp[8];
      #pragma unroll
      for (int r = 0; r < 8; ++r)
        rp[r] = acc[r][0] * wrb0 + acc[r][1] * wrb1;
      #pragma unroll
      for (int sh = 1; sh < 32; sh <<= 1) {
        #pragma unroll
        for (int r = 0; r < 8; ++r) rp[r] += __shfl_xor(rp[r], sh, 64);
      }
      if (lc == 0) {
        #pragma unroll
        for (int r = 0; r < 8; ++r) atomicAdd(&sret[r0 + r], rp[r]);
      }
      // s part
      float sp[4];
      #pragma unroll
      for (int i = 0; i < 4; ++i) {
        float sv = tanhf(sacc[i] + pT[(r0s + i) * kZ + cs] + bsv);
        sp[i] = sv * wrsv;
      }
      #pragma unroll
      for (int sh = 1; sh < 16; sh <<= 1) {
        #pragma unroll
        for (int i = 0; i < 4; ++i) sp[i] += __shfl_xor(sp[i], sh, 64);
      }
      if (lc2 == 0) {
        #pragma unroll
        for (int i = 0; i < 4; ++i) atomicAdd(&sret[r0s + i], sp[i]);
      }
    }
    __syncthreads();   // end of step
  }
  if (tid < kRowsB) ret[row0 + tid] = sret[tid];
}

// ---------------- per-batch top-k + statistics -----------------------------
__global__ __launch_bounds__(256) void k_topk_stats(
    const float* __restrict__ ret, const float* __restrict__ discA,
    const float* __restrict__ contA, float* __restrict__ freq,
    float* __restrict__ lfreq, float* __restrict__ meanv,
    float* __restrict__ stdv) {
  __shared__ float rv[kCand];
  __shared__ int selc[kTopK];
  __shared__ int hist[kTools];
  const int b = blockIdx.x, tid = threadIdx.x;
  for (int i = tid; i < kCand; i += 256) rv[i] = ret[b * kCand + i];
  __syncthreads();
  for (int c = tid; c < kCand; c += 256) {
    float v = rv[c];
    int rank = 0;
    for (int o = 0; o < kCand; ++o) {
      float vo = rv[o];
      rank += ((vo > v) || (vo == v && o < c)) ? 1 : 0;
    }
    if (rank < kTopK) selc[rank] = c;
  }
  __syncthreads();
  for (int ph = 0; ph < kPH; ++ph) {
    if (tid < kTools) hist[tid] = 0;
    __syncthreads();
    if (tid < kTopK) {
      int c = selc[tid];
      int idx = ph * kRT + b * kCand + c;
      int d = (int)discA[idx];
      atomicAdd(&hist[d], 1);
      float c0 = contA[idx * 2 + 0];
      float c1 = contA[idx * 2 + 1];
      float s0 = c0, s1 = c1;
      #pragma unroll
      for (int sh = 1; sh < 64; sh <<= 1) {
        s0 += __shfl_xor(s0, sh, 64);
        s1 += __shfl_xor(s1, sh, 64);
      }
      float m0 = s0 * (1.0f / 64.0f);
      float m1 = s1 * (1.0f / 64.0f);
      float d0 = c0 - m0, d1 = c1 - m1;
      float q0 = d0 * d0, q1 = d1 * d1;
      #pragma unroll
      for (int sh = 1; sh < 64; sh <<= 1) {
        q0 += __shfl_xor(q0, sh, 64);
        q1 += __shfl_xor(q1, sh, 64);
      }
      if (tid == 0) {
        int o = (ph * kB + b) * 2;
        meanv[o + 0] = m0;
        meanv[o + 1] = m1;
        stdv[o + 0] = sqrtf(q0 * (1.0f / 64.0f));
        stdv[o + 1] = sqrtf(q1 * (1.0f / 64.0f));
      }
    }
    __syncthreads();
    if (tid < kTools) {
      float fq = (float)(hist[tid] + 1) / 100.0f;
      int o = (ph * kB + b) * kTools + tid;
      freq[o] = fq;
      lfreq[o] = (float)log((double)fq);
    }
    __syncthreads();
  }
}

// ---------------- final output ---------------------------------------------
__global__ void k_final(const float* __restrict__ freq,
                        const float* __restrict__ meanv,
                        float* __restrict__ out) {
  int b = threadIdx.x;
  if (b < kB) {
    const float* f = freq + b * kTools;   // ph = 0
    int best = 0; float bv = f[0];
    for (int t = 1; t < kTools; ++t)
      if (f[t] > bv) { bv = f[t]; best = t; }
    out[b * 3 + 0] = (float)best;
    out[b * 3 + 1] = meanv[b * 2 + 0];
    out[b * 3 + 2] = meanv[b * 2 + 1];
  }
}

extern "C" void kernel_launch(void* const* d_in, const int* in_sizes, int n_in,
                              void* d_out, int out_size, void* d_ws, size_t ws_size,
                              hipStream_t stream) {
  (void)in_sizes; (void)n_in; (void)out_size; (void)ws_size;
  const float* belief = (const float*)d_in[0];
  const float* Wb  = (const float*)d_in[2];
  const float* Wa  = (const float*)d_in[3];
  const float* bb  = (const float*)d_in[4];
  const float* Ws  = (const float*)d_in[5];
  const float* bs  = (const float*)d_in[6];
  const float* wrb = (const float*)d_in[7];
  const float* wrs = (const float*)d_in[8];
  float* out = (float*)d_out;

  float* w = (float*)d_ws;
  float* discA = w;                          // PH*RT
  float* contA = discA + kPH * kRT;          // PH*RT*2
  float* ret   = contA + kPH * kRT * 2;      // RT
  float* freq  = ret + kRT;                  // PH*B*NTOOLS
  float* lfreq = freq + kPH * kB * kTools;   // PH*B*NTOOLS
  float* meanv = lfreq + kPH * kB * kTools;  // PH*B*2
  float* stdv  = meanv + kPH * kB * 2;       // PH*B*2

  uint32_t key0 = 0u, key1 = 42u;            // jax.random.key(42)
  for (int it = 0; it < 3; ++it) {
    uint32_t ks[3][2];
    host_split3(key0, key1, ks);
    int it0 = (it == 0) ? 1 : 0;
    k_sample_disc<<<dim3((kCand * kPH * kB + 255) / 256), dim3(256), 0, stream>>>(
        ks[0][0], ks[0][1], lfreq, discA, it0);
    k_sample_cont<<<dim3((kContTotal + 255) / 256), dim3(256), 0, stream>>>(
        ks[1][0], ks[1][1], meanv, stdv, contA, it0);
    k_rollout<<<dim3(kRT / kRowsB), dim3(512), 0, stream>>>(
        belief, discA, contA, Wb, Wa, bb, Ws, bs, wrb, wrs, ret);
    k_topk_stats<<<dim3(kB), dim3(256), 0, stream>>>(
        ret, discA, contA, freq, lfreq, meanv, stdv);
    key0 = ks[2][0]; key1 = ks[2][1];
  }
  k_final<<<dim3(1), dim3(64), 0, stream>>>(freq, meanv, out);
}

// Round 3
// 1082.501 us; speedup vs baseline: 2.4839x; 1.1071x over previous
//
#include <hip/hip_runtime.h>
#include <cstdint>
#include <cmath>

#define PARTITIONABLE 1

constexpr int kPH = 12;
constexpr int kB = 16;
constexpr int kH = 256;
constexpr int kZ = 64;
constexpr int kCand = 512;
constexpr int kTopK = 64;
constexpr int kTools = 36;
constexpr int kRT = kB * kCand;   // 8192 rows
constexpr uint32_t kDiscTotal = (uint32_t)kCand * kPH * kB * kTools; // 3538944
constexpr uint32_t kContTotal = (uint32_t)kPH * kB * kCand * 2;      // 196608

constexpr int kRowsB = 16;        // rows per rollout block
constexpr int kStrideB = 20;      // padded LDS stride (words); 80B = 16B-aligned

// ---------------- Threefry-2x32 (JAX-exact: 20 rounds, 5 key injections) ---
__host__ __device__ inline void tf2x32(uint32_t k0, uint32_t k1,
                                       uint32_t x0, uint32_t x1,
                                       uint32_t& o0, uint32_t& o1) {
  uint32_t ks2 = k0 ^ k1 ^ 0x1BD11BDAu;
  x0 += k0; x1 += k1;
#define TFROT(v, d) (((v) << (d)) | ((v) >> (32 - (d))))
#define TFR(r) { x0 += x1; x1 = TFROT(x1, r); x1 ^= x0; }
  TFR(13) TFR(15) TFR(26) TFR(6)
  x0 += k1;  x1 += ks2 + 1u;
  TFR(17) TFR(29) TFR(16) TFR(24)
  x0 += ks2; x1 += k0 + 2u;
  TFR(13) TFR(15) TFR(26) TFR(6)
  x0 += k0;  x1 += k1 + 3u;
  TFR(17) TFR(29) TFR(16) TFR(24)
  x0 += k1;  x1 += ks2 + 4u;
  TFR(13) TFR(15) TFR(26) TFR(6)
  x0 += ks2; x1 += k0 + 5u;
#undef TFR
#undef TFROT
  o0 = x0; o1 = x1;
}

__device__ inline uint32_t jax_bits32(uint32_t k0, uint32_t k1,
                                      uint32_t idx, uint32_t total) {
#if PARTITIONABLE
  (void)total;
  uint32_t y0, y1;
  tf2x32(k0, k1, 0u, idx, y0, y1);
  return y0 ^ y1;
#else
  uint32_t half = total >> 1;
  uint32_t y0, y1;
  if (idx < half) { tf2x32(k0, k1, idx, idx + half, y0, y1); return y0; }
  else            { tf2x32(k0, k1, idx - half, idx, y0, y1); return y1; }
#endif
}

static void host_split3(uint32_t k0, uint32_t k1, uint32_t out[3][2]) {
#if PARTITIONABLE
  for (uint32_t i = 0; i < 3; ++i)
    tf2x32(k0, k1, 0u, i, out[i][0], out[i][1]);
#else
  uint32_t a0,a1,b0,b1,c0,c1;
  tf2x32(k0, k1, 0u, 3u, a0, a1);
  tf2x32(k0, k1, 1u, 4u, b0, b1);
  tf2x32(k0, k1, 2u, 5u, c0, c1);
  out[0][0]=a0; out[0][1]=b0;
  out[1][0]=c0; out[1][1]=a1;
  out[2][0]=b1; out[2][1]=c1;
#endif
}

// ---------------- XLA f32 erf_inv (Giles polynomial) -----------------------
__device__ inline float erfinv_xla(float x) {
  float xx = x * x;
  float w = -(float)log1p((double)(-xx));
  float p;
  if (w < 5.0f) {
    float ww = w - 2.5f;
    p = 2.81022636e-08f;
    p = fmaf(p, ww, 3.43273939e-07f);
    p = fmaf(p, ww, -3.5233877e-06f);
    p = fmaf(p, ww, -4.39150654e-06f);
    p = fmaf(p, ww, 0.00021858087f);
    p = fmaf(p, ww, -0.00125372503f);
    p = fmaf(p, ww, -0.00417768164f);
    p = fmaf(p, ww, 0.246640727f);
    p = fmaf(p, ww, 1.50140941f);
  } else {
    float ww = sqrtf(w) - 3.0f;
    p = -0.000200214257f;
    p = fmaf(p, ww, 0.000100950558f);
    p = fmaf(p, ww, 0.00134934322f);
    p = fmaf(p, ww, -0.00367342844f);
    p = fmaf(p, ww, 0.00573950773f);
    p = fmaf(p, ww, -0.0076224613f);
    p = fmaf(p, ww, 0.00943887047f);
    p = fmaf(p, ww, 1.00167406f);
    p = fmaf(p, ww, 2.83297682f);
  }
  return p * x;
}

// ---------------- categorical sampling (disc actions) ----------------------
__global__ __launch_bounds__(256) void k_sample_disc(
    uint32_t kd0, uint32_t kd1, const float* __restrict__ lfreq,
    float* __restrict__ discA, int it0) {
  int gid = blockIdx.x * 256 + threadIdx.x;   // gid = c*(PH*B) + j
  if (gid >= kCand * kPH * kB) return;
  int c = gid / (kPH * kB);
  int j = gid - c * (kPH * kB);               // j = ph*16 + b
  int best = 0;
  if (it0) {
    uint32_t bm = 0u;
    for (int t = 0; t < kTools; ++t) {
      uint32_t bits = jax_bits32(kd0, kd1, (uint32_t)(gid * kTools + t), kDiscTotal);
      uint32_t m = bits >> 9;
      if (t == 0 || m > bm) { bm = m; best = t; }
    }
  } else {
    const float* lf = lfreq + j * kTools;
    float bv = 0.0f;
    for (int t = 0; t < kTools; ++t) {
      uint32_t bits = jax_bits32(kd0, kd1, (uint32_t)(gid * kTools + t), kDiscTotal);
      float u = __uint_as_float((bits >> 9) | 0x3F800000u) - 1.0f;
      if (u == 0.0f) u = 1.17549435e-38f;
      float l1 = (float)log((double)u);
      float g = -(float)log((double)(-l1));
      float val = g + lf[t];
      if (t == 0 || val > bv) { bv = val; best = t; }
    }
  }
  int ph = j >> 4, b = j & 15;
  discA[ph * kRT + b * kCand + c] = (float)best;
}

// ---------------- normal sampling (cont actions) ---------------------------
__global__ __launch_bounds__(256) void k_sample_cont(
    uint32_t kn0, uint32_t kn1, const float* __restrict__ meanv,
    const float* __restrict__ stdv, float* __restrict__ contA, int it0) {
  int gid = blockIdx.x * 256 + threadIdx.x;
  if (gid >= (int)kContTotal) return;
  uint32_t bits = jax_bits32(kn0, kn1, (uint32_t)gid, kContTotal);
  float f = __uint_as_float((bits >> 9) | 0x3F800000u) - 1.0f;
  const float lo = -0.99999994f;
  float u = fmaxf(lo, f * 2.0f + lo);
  float n = __uint_as_float(0x3FB504F3u) * erfinv_xla(u);
  int d = gid & 1;
  int c = (gid >> 1) & (kCand - 1);
  int rest = gid >> 10;                        // ph*16 + b
  int ph = rest >> 4, b = rest & 15;
  float m, s;
  if (it0) { m = 0.0f; s = 1.0f; }
  else {
    m = meanv[rest * 2 + d];
    s = stdv[rest * 2 + d];
  }
  float x = m + s * n;
  x = fminf(fmaxf(x, -1.0f), 1.0f);
  contA[(ph * kRT + b * kCand + c) * 2 + d] = x;
}

// ---------------- fused 12-step rollout ------------------------------------
// 512 blocks x 16 rows x 512 threads (8 waves). Wave (kw, wc): k-half kw,
// column-quarter wc. Thread tile: 4 rows x 4 cols (1 ds_read_b128 + 1
// global float4 + 16 FMA per k). Returns accumulate in registers across all
// 12 steps; 3 barriers per step.
__global__ __launch_bounds__(512, 4) void k_rollout(
    const float* __restrict__ belief,
    const float* __restrict__ discA, const float* __restrict__ contA,
    const float* __restrict__ Wb, const float* __restrict__ Wa,
    const float* __restrict__ bbv_, const float* __restrict__ Ws,
    const float* __restrict__ bs_, const float* __restrict__ wrb,
    const float* __restrict__ wrs, float* __restrict__ ret) {
  __shared__ float sBc[kH * kStrideB];        // 20 KB col-major belief [k][r]
  __shared__ float pT[kRowsB * kH];           // 16 KB b-partials
  __shared__ float sPT[kRowsB * kZ];          // 4 KB s-partials
  __shared__ float sAD[kPH][kRowsB];
  __shared__ float sA0[kPH][kRowsB];
  __shared__ float sA1[kPH][kRowsB];
  __shared__ float sret[kRowsB];

  const int tid = threadIdx.x;
  const int row0 = blockIdx.x * kRowsB;
  const int batch = row0 >> 9;

  const int w = tid >> 6;
  const int kw = w >> 2;            // k-half (0/1)
  const int wc = w & 3;             // column quarter
  const int lane = tid & 63;
  const int lr = lane >> 4;         // row group 0..3
  const int lc = lane & 15;
  const int r0 = lr * 4;            // rows r0..r0+3
  const int c0 = wc * 64 + lc * 4;  // cols c0..c0+3
  const int zc = wc * 16 + lc;      // s-column
  const int kbase = kw * 128;

  // loop-invariant params (finalize path, kw==0 uses them)
  const float4 bb4  = *reinterpret_cast<const float4*>(&bbv_[c0]);
  const float4 wa04 = *reinterpret_cast<const float4*>(&Wa[c0]);
  const float4 wa14 = *reinterpret_cast<const float4*>(&Wa[kH + c0]);
  const float4 wa24 = *reinterpret_cast<const float4*>(&Wa[2 * kH + c0]);
  const float4 wrb4 = *reinterpret_cast<const float4*>(&wrb[c0]);
  const float bsv = bs_[zc], wrsv = wrs[zc];

  // stage belief (col-major, replicated across 16 rows)
  if (tid < kH) {
    float v = belief[batch * kH + tid];
    #pragma unroll
    for (int r = 0; r < kRowsB; ++r) sBc[tid * kStrideB + r] = v;
  }
  // stage all 12 steps of actions
  for (int i = tid; i < kPH * kRowsB; i += 512) {
    int ph = i >> 4, r = i & 15;
    int gr = row0 + r;
    sAD[ph][r] = discA[ph * kRT + gr];
    sA0[ph][r] = contA[(ph * kRT + gr) * 2 + 0];
    sA1[ph][r] = contA[(ph * kRT + gr) * 2 + 1];
  }
  if (tid < kRowsB) sret[tid] = 0.0f;

  float rsum[4] = {0.0f, 0.0f, 0.0f, 0.0f};
  float ssum[4] = {0.0f, 0.0f, 0.0f, 0.0f};
  __syncthreads();

  const float* bK = sBc + kbase * kStrideB + r0;          // LDS base
  const float* wB = Wb + (size_t)kbase * kH + c0;         // global Wb base
  const float* wS = Ws + (size_t)kbase * kZ + zc;         // global Ws base

  #pragma unroll 1
  for (int ph = 0; ph < kPH; ++ph) {
    // ---- b' = tanh(b @ Wb + a @ Wa + bb), k-half outer product ----
    float acc[4][4];
    #pragma unroll
    for (int r = 0; r < 4; ++r)
      #pragma unroll
      for (int c = 0; c < 4; ++c) acc[r][c] = 0.0f;
    #pragma unroll 4
    for (int k = 0; k < 128; ++k) {
      float4 bv = *reinterpret_cast<const float4*>(bK + k * kStrideB);
      float4 wv = *reinterpret_cast<const float4*>(wB + k * kH);
      acc[0][0] = fmaf(bv.x, wv.x, acc[0][0]);
      acc[0][1] = fmaf(bv.x, wv.y, acc[0][1]);
      acc[0][2] = fmaf(bv.x, wv.z, acc[0][2]);
      acc[0][3] = fmaf(bv.x, wv.w, acc[0][3]);
      acc[1][0] = fmaf(bv.y, wv.x, acc[1][0]);
      acc[1][1] = fmaf(bv.y, wv.y, acc[1][1]);
      acc[1][2] = fmaf(bv.y, wv.z, acc[1][2]);
      acc[1][3] = fmaf(bv.y, wv.w, acc[1][3]);
      acc[2][0] = fmaf(bv.z, wv.x, acc[2][0]);
      acc[2][1] = fmaf(bv.z, wv.y, acc[2][1]);
      acc[2][2] = fmaf(bv.z, wv.z, acc[2][2]);
      acc[2][3] = fmaf(bv.z, wv.w, acc[2][3]);
      acc[3][0] = fmaf(bv.w, wv.x, acc[3][0]);
      acc[3][1] = fmaf(bv.w, wv.y, acc[3][1]);
      acc[3][2] = fmaf(bv.w, wv.z, acc[3][2]);
      acc[3][3] = fmaf(bv.w, wv.w, acc[3][3]);
    }
    if (kw == 1) {
      #pragma unroll
      for (int r = 0; r < 4; ++r)
        *reinterpret_cast<float4*>(&pT[(r0 + r) * kH + c0]) =
            make_float4(acc[r][0], acc[r][1], acc[r][2], acc[r][3]);
    }
    __syncthreads();                          // (1) pT ready; old sBc free
    if (kw == 0) {
      #pragma unroll
      for (int r = 0; r < 4; ++r) {
        float4 p = *reinterpret_cast<const float4*>(&pT[(r0 + r) * kH + c0]);
        float aD = sAD[ph][r0 + r], a0 = sA0[ph][r0 + r], a1 = sA1[ph][r0 + r];
        float t0 = acc[r][0] + p.x + bb4.x + aD * wa04.x + a0 * wa14.x + a1 * wa24.x;
        float t1 = acc[r][1] + p.y + bb4.y + aD * wa04.y + a0 * wa14.y + a1 * wa24.y;
        float t2 = acc[r][2] + p.z + bb4.z + aD * wa04.z + a0 * wa14.z + a1 * wa24.z;
        float t3 = acc[r][3] + p.w + bb4.w + aD * wa04.w + a0 * wa14.w + a1 * wa24.w;
        acc[r][0] = tanhf(t0);
        acc[r][1] = tanhf(t1);
        acc[r][2] = tanhf(t2);
        acc[r][3] = tanhf(t3);
      }
      // write b' col-major
      #pragma unroll
      for (int c = 0; c < 4; ++c)
        *reinterpret_cast<float4*>(&sBc[(c0 + c) * kStrideB + r0]) =
            make_float4(acc[0][c], acc[1][c], acc[2][c], acc[3][c]);
      // returns: belief part, accumulate in registers
      #pragma unroll
      for (int r = 0; r < 4; ++r) {
        rsum[r] = fmaf(acc[r][0], wrb4.x, rsum[r]);
        rsum[r] = fmaf(acc[r][1], wrb4.y, rsum[r]);
        rsum[r] = fmaf(acc[r][2], wrb4.z, rsum[r]);
        rsum[r] = fmaf(acc[r][3], wrb4.w, rsum[r]);
      }
    }
    __syncthreads();                          // (2) new belief visible

    // ---- s = tanh(b' @ Ws + bs), k-half outer product ----
    float sa[4] = {0.0f, 0.0f, 0.0f, 0.0f};
    #pragma unroll 8
    for (int k = 0; k < 128; ++k) {
      float4 bv = *reinterpret_cast<const float4*>(bK + k * kStrideB);
      float wv = wS[k * kZ];
      sa[0] = fmaf(bv.x, wv, sa[0]);
      sa[1] = fmaf(bv.y, wv, sa[1]);
      sa[2] = fmaf(bv.z, wv, sa[2]);
      sa[3] = fmaf(bv.w, wv, sa[3]);
    }
    if (kw == 1) {
      #pragma unroll
      for (int r = 0; r < 4; ++r) sPT[(r0 + r) * kZ + zc] = sa[r];
    }
    __syncthreads();                          // (3) s-partials ready
    if (kw == 0) {
      #pragma unroll
      for (int r = 0; r < 4; ++r) {
        float sv = tanhf(sa[r] + sPT[(r0 + r) * kZ + zc] + bsv);
        ssum[r] = fmaf(sv, wrsv, ssum[r]);
      }
    }
    // no barrier: kw1's next pT/sPT writes are separated by >=2 barriers
    // from this step's kw0 reads.
  }

  // final: reduce rsum+ssum over lc lanes (cols / z within wave), then wc
  if (kw == 0) {
    #pragma unroll
    for (int r = 0; r < 4; ++r) {
      float v = rsum[r] + ssum[r];
      v += __shfl_xor(v, 1, 64);
      v += __shfl_xor(v, 2, 64);
      v += __shfl_xor(v, 4, 64);
      v += __shfl_xor(v, 8, 64);
      if (lc == 0) atomicAdd(&sret[r0 + r], v);
    }
  }
  __syncthreads();
  if (tid < kRowsB) ret[row0 + tid] = sret[tid];
}

// ---------------- per-batch top-k + statistics -----------------------------
__global__ __launch_bounds__(256) void k_topk_stats(
    const float* __restrict__ ret, const float* __restrict__ discA,
    const float* __restrict__ contA, float* __restrict__ freq,
    float* __restrict__ lfreq, float* __restrict__ meanv,
    float* __restrict__ stdv) {
  __shared__ float rv[kCand];
  __shared__ int selc[kTopK];
  __shared__ int hist[kTools];
  const int b = blockIdx.x, tid = threadIdx.x;
  for (int i = tid; i < kCand; i += 256) rv[i] = ret[b * kCand + i];
  __syncthreads();
  for (int c = tid; c < kCand; c += 256) {
    float v = rv[c];
    int rank = 0;
    for (int o = 0; o < kCand; ++o) {
      float vo = rv[o];
      rank += ((vo > v) || (vo == v && o < c)) ? 1 : 0;
    }
    if (rank < kTopK) selc[rank] = c;
  }
  __syncthreads();
  for (int ph = 0; ph < kPH; ++ph) {
    if (tid < kTools) hist[tid] = 0;
    __syncthreads();
    if (tid < kTopK) {
      int c = selc[tid];
      int idx = ph * kRT + b * kCand + c;
      int d = (int)discA[idx];
      atomicAdd(&hist[d], 1);
      float c0 = contA[idx * 2 + 0];
      float c1 = contA[idx * 2 + 1];
      float s0 = c0, s1 = c1;
      #pragma unroll
      for (int sh = 1; sh < 64; sh <<= 1) {
        s0 += __shfl_xor(s0, sh, 64);
        s1 += __shfl_xor(s1, sh, 64);
      }
      float m0 = s0 * (1.0f / 64.0f);
      float m1 = s1 * (1.0f / 64.0f);
      float d0 = c0 - m0, d1 = c1 - m1;
      float q0 = d0 * d0, q1 = d1 * d1;
      #pragma unroll
      for (int sh = 1; sh < 64; sh <<= 1) {
        q0 += __shfl_xor(q0, sh, 64);
        q1 += __shfl_xor(q1, sh, 64);
      }
      if (tid == 0) {
        int o = (ph * kB + b) * 2;
        meanv[o + 0] = m0;
        meanv[o + 1] = m1;
        stdv[o + 0] = sqrtf(q0 * (1.0f / 64.0f));
        stdv[o + 1] = sqrtf(q1 * (1.0f / 64.0f));
      }
    }
    __syncthreads();
    if (tid < kTools) {
      float fq = (float)(hist[tid] + 1) / 100.0f;
      int o = (ph * kB + b) * kTools + tid;
      freq[o] = fq;
      lfreq[o] = (float)log((double)fq);
    }
    __syncthreads();
  }
}

// ---------------- final output ---------------------------------------------
__global__ void k_final(const float* __restrict__ freq,
                        const float* __restrict__ meanv,
                        float* __restrict__ out) {
  int b = threadIdx.x;
  if (b < kB) {
    const float* f = freq + b * kTools;   // ph = 0
    int best = 0; float bv = f[0];
    for (int t = 1; t < kTools; ++t)
      if (f[t] > bv) { bv = f[t]; best = t; }
    out[b * 3 + 0] = (float)best;
    out[b * 3 + 1] = meanv[b * 2 + 0];
    out[b * 3 + 2] = meanv[b * 2 + 1];
  }
}

extern "C" void kernel_launch(void* const* d_in, const int* in_sizes, int n_in,
                              void* d_out, int out_size, void* d_ws, size_t ws_size,
                              hipStream_t stream) {
  (void)in_sizes; (void)n_in; (void)out_size; (void)ws_size;
  const float* belief = (const float*)d_in[0];
  const float* Wb  = (const float*)d_in[2];
  const float* Wa  = (const float*)d_in[3];
  const float* bb  = (const float*)d_in[4];
  const float* Ws  = (const float*)d_in[5];
  const float* bs  = (const float*)d_in[6];
  const float* wrb = (const float*)d_in[7];
  const float* wrs = (const float*)d_in[8];
  float* out = (float*)d_out;

  float* w = (float*)d_ws;
  float* discA = w;                          // PH*RT
  float* contA = discA + kPH * kRT;          // PH*RT*2
  float* ret   = contA + kPH * kRT * 2;      // RT
  float* freq  = ret + kRT;                  // PH*B*NTOOLS
  float* lfreq = freq + kPH * kB * kTools;   // PH*B*NTOOLS
  float* meanv = lfreq + kPH * kB * kTools;  // PH*B*2
  float* stdv  = meanv + kPH * kB * 2;       // PH*B*2

  uint32_t key0 = 0u, key1 = 42u;            // jax.random.key(42)
  for (int it = 0; it < 3; ++it) {
    uint32_t ks[3][2];
    host_split3(key0, key1, ks);
    int it0 = (it == 0) ? 1 : 0;
    k_sample_disc<<<dim3((kCand * kPH * kB + 255) / 256), dim3(256), 0, stream>>>(
        ks[0][0], ks[0][1], lfreq, discA, it0);
    k_sample_cont<<<dim3((kContTotal + 255) / 256), dim3(256), 0, stream>>>(
        ks[1][0], ks[1][1], meanv, stdv, contA, it0);
    k_rollout<<<dim3(kRT / kRowsB), dim3(512), 0, stream>>>(
        belief, discA, contA, Wb, Wa, bb, Ws, bs, wrb, wrs, ret);
    k_topk_stats<<<dim3(kB), dim3(256), 0, stream>>>(
        ret, discA, contA, freq, lfreq, meanv, stdv);
    key0 = ks[2][0]; key1 = ks[2][1];
  }
  k_final<<<dim3(1), dim3(64), 0, stream>>>(freq, meanv, out);
}